// Round 11
// baseline (53.995 us; speedup 1.0000x reference)
//
#include <hip/hip_runtime.h>
#include <math.h>

typedef __attribute__((ext_vector_type(8))) short bf16x8;
typedef __attribute__((ext_vector_type(8))) unsigned short u16x8;
typedef __attribute__((ext_vector_type(4))) float f32x4;

#define GLOAD_LDS16(g, l) __builtin_amdgcn_global_load_lds( \
    (const __attribute__((address_space(1))) unsigned int*)(g), \
    (__attribute__((address_space(3))) unsigned int*)(l), 16, 0, 0)

__device__ __forceinline__ unsigned short f2bf(float f) {
    unsigned int u = __builtin_bit_cast(unsigned int, f);
    unsigned int r = (u + 0x7FFFu + ((u >> 16) & 1)) >> 16;
    return (unsigned short)r;
}

__device__ __forceinline__ float sigmoidf_(float v) {
    return 1.f / (1.f + __expf(-v));
}

// Tiled-swizzled bf16 operand layout: 64x64 tiles (4096 elems), elem (r,k)
// stored at tileBase + r*64 + ((k>>3) ^ (r&7))*8 + (k&7).  This is the exact
// linear image global_load_lds DMAs into LDS; the GEMM's ds_read applies the
// same XOR -> conflict-free.  (r7-proven kernel, verbatim.)
// blocks 0..511: w [512][2048] -> wbf tiles (mt64*32+kt)
// blocks 512..1535: x4 [8][2048][256] -> xbf tiles: row n'=b*256+p, tile
// index (b*4+pg)*32+kt.
__global__ __launch_bounds__(256) void convert_kernel(
    const float* __restrict__ w, const float* __restrict__ x4,
    unsigned short* __restrict__ wbf, unsigned short* __restrict__ xbf)
{
    __shared__ float t[64][65];
    if (blockIdx.x < 512) {
        int f = blockIdx.x * 256 + threadIdx.x;      // ushort8 chunk id
        int tile = f >> 9, inner = f & 511;
        int r = inner >> 3, cc = inner & 7;
        int mt = tile >> 5, kt = tile & 31;
        const float* src = w + (mt * 64 + r) * 2048 + kt * 64 + cc * 8;
        float4 v0 = *(const float4*)src;
        float4 v1 = *(const float4*)(src + 4);
        u16x8 o;
        o[0] = f2bf(v0.x); o[1] = f2bf(v0.y); o[2] = f2bf(v0.z); o[3] = f2bf(v0.w);
        o[4] = f2bf(v1.x); o[5] = f2bf(v1.y); o[6] = f2bf(v1.z); o[7] = f2bf(v1.w);
        *(u16x8*)(wbf + (size_t)tile * 4096 + r * 64 + ((cc ^ (r & 7)) * 8)) = o;
        return;
    }
    // x path: LDS-transpose a 64k x 64p block, emit swizzled bf16 tile
    const int bi = blockIdx.x - 512;        // 0..1023
    const int b = bi >> 7, rem = bi & 127;
    const int kt = rem >> 2, pg = rem & 3;
    const float* src = x4 + ((size_t)b * 2048 + kt * 64) * 256 + pg * 64;
#pragma unroll
    for (int i = 0; i < 4; ++i) {
        int f = i * 256 + threadIdx.x;       // 0..1023 float4s = 64k x 64p
        int kk = f >> 4, pp4 = f & 15;
        float4 v = *(const float4*)(src + kk * 256 + pp4 * 4);
        t[pp4 * 4 + 0][kk] = v.x;
        t[pp4 * 4 + 1][kk] = v.y;
        t[pp4 * 4 + 2][kk] = v.z;
        t[pp4 * 4 + 3][kk] = v.w;
    }
    __syncthreads();
    unsigned short* dst = xbf + (size_t)((b * 4 + pg) * 32 + kt) * 4096;
#pragma unroll
    for (int i = 0; i < 2; ++i) {
        int inner = i * 256 + threadIdx.x;
        int r = inner >> 3, cc = inner & 7;
        u16x8 o;
#pragma unroll
        for (int j = 0; j < 8; ++j) o[j] = f2bf(t[r][cc * 8 + j]);
        *(u16x8*)(dst + r * 64 + ((cc ^ (r & 7)) * 8)) = o;
    }
}

// y4[b][m][p] = bias[m] + sum_k w[m][k]*x[n'][k],  n' = b*256+p.
// Tile 64m x 64p, full K=2048, BK=64; 256 blocks x 512 threads (8 waves,
// each a 16m x 32p sub-tile).  Staging: global_load_lds from pre-swizzled
// bf16 tiles (per-XCD L2 set: wbf 2MB + x-slab 1.05MB < 4MB -> L2-resident).
// blockIdx&7 = XCD = batch b.
__global__ __launch_bounds__(512) void gemm_bf16(
    const unsigned short* __restrict__ wbf, const unsigned short* __restrict__ xbf,
    const float* __restrict__ bias, float* __restrict__ y4,
    float* __restrict__ chanpart)
{
    __shared__ short As[2][4096];   // [buf][64m x 64k] swizzled
    __shared__ short Bs[2][4096];   // [buf][64p x 64k] swizzled

    const int tid = threadIdx.x;
    const int wave = tid >> 6, lane = tid & 63;
    const int wm = wave >> 1, wn = wave & 1;     // wm 0..3 (16m), wn 0..1 (32p)
    const int lr = lane & 15, lh = lane >> 4;

    const int flat = blockIdx.x;
    const int b = flat & 7;              // XCD-aligned batch
    const int j = flat >> 3;
    const int mt = j & 7;                // 0..7  (64-row chunk of M=512)
    const int nq = j >> 3;               // 0..3  (64-col chunk of one batch)

    const unsigned short* Abase = wbf + (size_t)(mt * 32) * 4096;
    const unsigned short* Bbase = xbf + (size_t)((b * 4 + nq) * 32) * 4096;

    // per k-tile: A 8KB (8 segs of 1024B) + B 8KB; wave w DMAs A-seg w, B-seg w
#define STAGE(buf, tt)                                                        \
    {                                                                         \
        GLOAD_LDS16(Abase + (size_t)(tt) * 4096 + wave * 512 + lane * 8,      \
                    &As[buf][wave * 512]);                                    \
        GLOAD_LDS16(Bbase + (size_t)(tt) * 4096 + wave * 512 + lane * 8,      \
                    &Bs[buf][wave * 512]);                                    \
    }

    STAGE(0, 0);
    __syncthreads();

    f32x4 acc0 = {}, acc1 = {};
    int cur = 0;
    for (int t = 0; t < 32; ++t) {
        if (t < 31) STAGE(cur ^ 1, t + 1);
#pragma unroll
        for (int kc = 0; kc < 2; ++kc) {
            const int ch = kc * 4 + lh;
            int rA  = wm * 16 + lr;
            int rB0 = wn * 32 + lr, rB1 = rB0 + 16;
            bf16x8 a0 = *(const bf16x8*)(&As[cur][rA  * 64 + ((ch ^ (rA  & 7)) * 8)]);
            bf16x8 b0 = *(const bf16x8*)(&Bs[cur][rB0 * 64 + ((ch ^ (rB0 & 7)) * 8)]);
            bf16x8 b1 = *(const bf16x8*)(&Bs[cur][rB1 * 64 + ((ch ^ (rB1 & 7)) * 8)]);
            acc0 = __builtin_amdgcn_mfma_f32_16x16x32_bf16(a0, b0, acc0, 0, 0, 0);
            acc1 = __builtin_amdgcn_mfma_f32_16x16x32_bf16(a0, b1, acc1, 0, 0, 0);
        }
        __syncthreads();
        cur ^= 1;
    }
#undef STAGE

    float* yb = y4 + ((size_t)b * 512 + mt * 64) * 256 + nq * 64;
#pragma unroll
    for (int rr = 0; rr < 4; ++rr) {
        const int m = wm * 16 + lh * 4 + rr;      // within 64-row tile
        const float bv = bias[mt * 64 + m];
        yb[m * 256 + wn * 32 + lr]      = acc0[rr] + bv;
        yb[m * 256 + wn * 32 + 16 + lr] = acc1[rr] + bv;
        // wave-local sum over its 32 n positions
        float s = acc0[rr] + acc1[rr];
        s += __shfl_xor(s, 1);
        s += __shfl_xor(s, 2);
        s += __shfl_xor(s, 4);
        s += __shfl_xor(s, 8);
        if (lr == 0)
            chanpart[(size_t)(b * 512 + mt * 64 + m) * 8 + nq * 2 + wn] = s + 32.f * bv;
    }
}

// Per (bg, p-chunk of 32): fc1+fc2 (redundant per chunk, cheap), sa dot over
// 256 channels, deterministic gsum partial.  512 blocks x 256 threads.
__global__ __launch_bounds__(256) void sa_kernel(
    const float* __restrict__ y4, const float* __restrict__ chanpart,
    const float* __restrict__ fc1w, const float* __restrict__ fc1b,
    const float* __restrict__ fc2w, const float* __restrict__ fc2b,
    const float* __restrict__ saw, const float* __restrict__ sab,
    float* __restrict__ ca, float* __restrict__ sa, float* __restrict__ gsums)
{
    const int blk = blockIdx.x;
    const int bg = blk >> 3, pc = blk & 7;
    const int b = bg >> 3, g = bg & 7;
    const int tid = threadIdx.x;
    const float* xg = y4 + ((size_t)b * 512 + (g & 1) * 256) * 256 + pc * 32;

    __shared__ float xl[256][32];
    __shared__ float avgs[256], red[256], hs[64], cas[256], caws[256], sas[32];

    // stage y4 slice [256c][32p]
#pragma unroll
    for (int i = 0; i < 8; ++i) {
        int f = i * 256 + tid;            // float4 id, 2048 total
        int c = f >> 3, p4 = f & 7;
        float4 v = *(const float4*)(xg + c * 256 + p4 * 4);
        *(float4*)(&xl[c][p4 * 4]) = v;
    }
    {
        const float* cpp = chanpart + (size_t)(b * 512 + (g & 1) * 256 + tid) * 8;
        float cp = 0.f;
#pragma unroll
        for (int i = 0; i < 8; ++i) cp += cpp[i];
        avgs[tid] = cp * (1.f / 256.f);
    }
    __syncthreads();
    // fc1: 256 -> 64, relu
    {
        int o = tid & 63, seg = tid >> 6;
        const float* wr = fc1w + (g * 64 + o) * 256 + seg * 64;
        const float* av = avgs + seg * 64;
        float s = 0.f;
#pragma unroll
        for (int i = 0; i < 64; ++i) s = fmaf(av[i], wr[i], s);
        red[tid] = s;
    }
    __syncthreads();
    if (tid < 64) {
        float s = fc1b[g * 64 + tid] + red[tid] + red[64 + tid] + red[128 + tid] + red[192 + tid];
        hs[tid] = fmaxf(s, 0.f);
    }
    __syncthreads();
    // fc2: 64 -> 256, sigmoid
    {
        const float* wr = fc2w + (g * 256 + tid) * 64;
        float s = fc2b[g * 256 + tid];
#pragma unroll
        for (int i = 0; i < 64; ++i) s = fmaf(hs[i], wr[i], s);
        float v = sigmoidf_(s);
        cas[tid] = v;
        caws[tid] = v * saw[g * 256 + tid];
        if (pc == 0) ca[bg * 256 + tid] = v;
    }
    __syncthreads();
    // sa dot over channels for 32 positions (from LDS)
    const int p_l = tid & 31, seg8 = tid >> 5;
    {
        float s = 0.f;
#pragma unroll
        for (int i = 0; i < 32; ++i) {
            int c = seg8 * 32 + i;
            s = fmaf(xl[c][p_l], caws[c], s);
        }
        red[tid] = s;
    }
    __syncthreads();
    if (tid < 32) {
        float s = sab[g];
#pragma unroll
        for (int k = 0; k < 8; ++k) s += red[k * 32 + tid];
        float v = sigmoidf_(s);
        sas[tid] = v;
        sa[bg * 256 + pc * 32 + tid] = v;
    }
    __syncthreads();
    // gsum partial: sum sigmoid(x*ca*sa) over this chunk's 32p x 256c
    {
        float sv = sas[p_l];
        float s = 0.f;
#pragma unroll
        for (int i = 0; i < 32; ++i) {
            int c = seg8 * 32 + i;
            s += sigmoidf_(xl[c][p_l] * cas[c] * sv);
        }
        red[tid] = s;
    }
    __syncthreads();
    for (int off = 128; off > 0; off >>= 1) {
        if (tid < off) red[tid] += red[tid + off];
        __syncthreads();
    }
    if (tid == 0) gsums[blk] = red[0];
}

// out = x*(1+mask); mask = (y>mean)?1:y, y = sigmoid(x*ca*sa)
__global__ __launch_bounds__(256) void final_kernel(
    const float* __restrict__ y4, const float* __restrict__ ca,
    const float* __restrict__ sa, const float* __restrict__ gsums,
    float* __restrict__ out)
{
    int f = blockIdx.x * 256 + threadIdx.x;   // float4 index, 1048576 total
    int p4 = f & 63, ch = (f >> 6) & 2047, b = f >> 17;
    int g = ch >> 8, c = ch & 255, bg = b * 8 + g;
    const float4 x = *(const float4*)(y4 + ((size_t)b * 512 + (g & 1) * 256 + c) * 256 + p4 * 4);
    float cav = ca[bg * 256 + c];
    const float4 sv = *(const float4*)(sa + bg * 256 + p4 * 4);
    float msum = 0.f;
#pragma unroll
    for (int i = 0; i < 8; ++i) msum += gsums[bg * 8 + i];
    float mean = msum * (1.f / 65536.f);
    float4 o;
#define DOLANE(X) { float yv = sigmoidf_(x.X * cav * sv.X); float mk = (yv > mean) ? 1.f : yv; o.X = x.X * (1.f + mk); }
    DOLANE(x) DOLANE(y) DOLANE(z) DOLANE(w)
#undef DOLANE
    *(float4*)(out + (size_t)f * 4) = o;
}

extern "C" void kernel_launch(void* const* d_in, const int* in_sizes, int n_in,
                              void* d_out, int out_size, void* d_ws, size_t ws_size,
                              hipStream_t stream) {
    const float* x4   = (const float*)d_in[3];
    const float* w4   = (const float*)d_in[10];
    const float* b4   = (const float*)d_in[11];
    const float* fc1w = (const float*)d_in[12];
    const float* fc1b = (const float*)d_in[13];
    const float* fc2w = (const float*)d_in[14];
    const float* fc2b = (const float*)d_in[15];
    const float* saw  = (const float*)d_in[16];
    const float* sab  = (const float*)d_in[17];
    float* out = (float*)d_out;

    float* ws = (float*)d_ws;
    float* y4       = ws;                    // 1048576
    float* ca       = ws + 1048576;          // 16384
    float* saBuf    = ws + 1064960;          // 16384
    float* gsums    = ws + 1081344;          // 512
    float* chanpart = ws + 1081856;          // 32768
    unsigned short* wbf = (unsigned short*)(ws + 1114624);  // 1048576 bf16
    unsigned short* xbf = (unsigned short*)(ws + 1638912);  // 4194304 bf16

    convert_kernel<<<dim3(1536), dim3(256), 0, stream>>>(w4, x4, wbf, xbf);
    gemm_bf16<<<dim3(256), dim3(512), 0, stream>>>(wbf, xbf, b4, y4, chanpart);
    sa_kernel<<<dim3(512), dim3(256), 0, stream>>>(y4, chanpart, fc1w, fc1b, fc2w, fc2b,
                                                   saw, sab, ca, saBuf, gsums);
    final_kernel<<<dim3(4096), dim3(256), 0, stream>>>(y4, ca, saBuf, gsums, out);
}

// Round 12
// 44.256 us; speedup vs baseline: 1.2200x; 1.2200x over previous
//
#include <hip/hip_runtime.h>
#include <math.h>

typedef __attribute__((ext_vector_type(8))) short bf16x8;
typedef __attribute__((ext_vector_type(8))) unsigned short u16x8;
typedef __attribute__((ext_vector_type(4))) float f32x4;

__device__ __forceinline__ unsigned short f2bf(float f) {
    unsigned int u = __builtin_bit_cast(unsigned int, f);
    unsigned int r = (u + 0x7FFFu + ((u >> 16) & 1)) >> 16;
    return (unsigned short)r;
}

__device__ __forceinline__ float sigmoidf_(float v) {
    return 1.f / (1.f + __expf(-v));
}

struct StageRegs { float4 w0, w1, x0, x1; };

// Fused convert+GEMM (r10-proven, verbatim).  y4[b][m][p] = bias[m] +
// sum_k w[m][k]*x4[b][k][p].  Tile 64m x 64p, full K=2048, BK=64.
// 512 threads = 8 waves, each a 16m x 32p sub-tile.  T14 distance-2 register
// pipeline, one barrier per K-tile.  XOR-swizzled LDS tiles: elem (r,k) at
// r*64 + ((k>>3)^(r&7))*8 + (k&7) shorts.  Grid 256; blockIdx&7 = XCD = b.
__global__ __launch_bounds__(512) void gemm_fused(
    const float* __restrict__ x4, const float* __restrict__ w,
    const float* __restrict__ bias, float* __restrict__ y4,
    float* __restrict__ chanpart)
{
    __shared__ short As[2][4096];   // [buf][64m x 64k] swizzled
    __shared__ short Bs[2][4096];   // [buf][64p x 64k] swizzled

    const int tid = threadIdx.x;
    const int wave = tid >> 6, lane = tid & 63;
    const int wm = wave >> 1, wn = wave & 1;     // wm 0..3 (16m), wn 0..1 (32p)
    const int lr = lane & 15, lh = lane >> 4;

    const int flat = blockIdx.x;
    const int b = flat & 7;              // XCD-aligned batch
    const int j = flat >> 3;
    const int mt = j & 7;                // 0..7  (64-row chunk of M=512)
    const int nq = j >> 3;               // 0..3  (64-col chunk of one batch)

    // staging roles (512 threads)
    const int ar = tid >> 3, ac = tid & 7;    // A: row 0..63, k-chunk(8) 0..7
    const int ku = tid >> 4, xp4 = tid & 15;  // B: k-pair 0..31, p-quad 0..15

    const float* wbase = w + (size_t)(mt * 64 + ar) * 2048 + ac * 8;
    const float* xbase = x4 + ((size_t)b * 2048 + 2 * ku) * 256 + nq * 64 + xp4 * 4;

#define LOADT(R, t) {                                                         \
        (R).w0 = *(const float4*)(wbase + (t) * 64);                          \
        (R).w1 = *(const float4*)(wbase + (t) * 64 + 4);                      \
        (R).x0 = *(const float4*)(xbase + (size_t)(t) * 64 * 256);            \
        (R).x1 = *(const float4*)(xbase + (size_t)(t) * 64 * 256 + 256); }
#define WRITET(buf, R) {                                                      \
        u16x8 o;                                                              \
        o[0] = f2bf((R).w0.x); o[1] = f2bf((R).w0.y);                         \
        o[2] = f2bf((R).w0.z); o[3] = f2bf((R).w0.w);                         \
        o[4] = f2bf((R).w1.x); o[5] = f2bf((R).w1.y);                         \
        o[6] = f2bf((R).w1.z); o[7] = f2bf((R).w1.w);                         \
        *(u16x8*)(&As[buf][ar * 64 + ((ac ^ (ar & 7)) * 8)]) = o;             \
        unsigned int pk0 = f2bf((R).x0.x) | ((unsigned int)f2bf((R).x1.x) << 16); \
        unsigned int pk1 = f2bf((R).x0.y) | ((unsigned int)f2bf((R).x1.y) << 16); \
        unsigned int pk2 = f2bf((R).x0.z) | ((unsigned int)f2bf((R).x1.z) << 16); \
        unsigned int pk3 = f2bf((R).x0.w) | ((unsigned int)f2bf((R).x1.w) << 16); \
        unsigned int* bs32 = (unsigned int*)&Bs[buf][0];                      \
        { int p = xp4 * 4 + 0;                                                \
          bs32[p * 32 + ((ku >> 2) ^ (p & 7)) * 4 + (ku & 3)] = pk0; }        \
        { int p = xp4 * 4 + 1;                                                \
          bs32[p * 32 + ((ku >> 2) ^ (p & 7)) * 4 + (ku & 3)] = pk1; }        \
        { int p = xp4 * 4 + 2;                                                \
          bs32[p * 32 + ((ku >> 2) ^ (p & 7)) * 4 + (ku & 3)] = pk2; }        \
        { int p = xp4 * 4 + 3;                                                \
          bs32[p * 32 + ((ku >> 2) ^ (p & 7)) * 4 + (ku & 3)] = pk3; } }
#define MFMA_TILE(cur) {                                                      \
        _Pragma("unroll")                                                     \
        for (int kc = 0; kc < 2; ++kc) {                                      \
            const int ch = kc * 4 + lh;                                       \
            int rA  = wm * 16 + lr;                                           \
            int rB0 = wn * 32 + lr, rB1 = rB0 + 16;                           \
            bf16x8 a0 = *(const bf16x8*)(&As[cur][rA  * 64 + ((ch ^ (rA  & 7)) * 8)]); \
            bf16x8 b0 = *(const bf16x8*)(&Bs[cur][rB0 * 64 + ((ch ^ (rB0 & 7)) * 8)]); \
            bf16x8 b1 = *(const bf16x8*)(&Bs[cur][rB1 * 64 + ((ch ^ (rB1 & 7)) * 8)]); \
            acc0 = __builtin_amdgcn_mfma_f32_16x16x32_bf16(a0, b0, acc0, 0, 0, 0); \
            acc1 = __builtin_amdgcn_mfma_f32_16x16x32_bf16(a0, b1, acc1, 0, 0, 0); \
        } }

    StageRegs Ra, Rb;
    // Prologue: tile0 -> buf0 (via Ra), tile1 -> Rb, tile2 -> Ra (in flight)
    LOADT(Ra, 0);
    WRITET(0, Ra);
    LOADT(Rb, 1);
    LOADT(Ra, 2);
    __syncthreads();

    f32x4 acc0 = {}, acc1 = {};
    for (int t = 0; t < 32; t += 2) {
        // even: consume buf0 (tile t); write buf1 <- tile t+1 (Rb, loaded 2
        // iters ago, vmcnt satisfied); issue load tile t+3 -> Rb
        WRITET(1, Rb);
        if (t < 29) LOADT(Rb, t + 3);
        MFMA_TILE(0);
        __syncthreads();
        // odd: consume buf1 (tile t+1); write buf0 <- tile t+2 (Ra); load t+4
        if (t < 30) {
            WRITET(0, Ra);
            if (t < 28) LOADT(Ra, t + 4);
        }
        MFMA_TILE(1);
        __syncthreads();
    }
#undef LOADT
#undef WRITET
#undef MFMA_TILE

    float* yb = y4 + ((size_t)b * 512 + mt * 64) * 256 + nq * 64;
#pragma unroll
    for (int rr = 0; rr < 4; ++rr) {
        const int m = wm * 16 + lh * 4 + rr;      // within 64-row tile
        const float bv = bias[mt * 64 + m];
        yb[m * 256 + wn * 32 + lr]      = acc0[rr] + bv;
        yb[m * 256 + wn * 32 + 16 + lr] = acc1[rr] + bv;
        // wave-local sum over its 32 n positions
        float s = acc0[rr] + acc1[rr];
        s += __shfl_xor(s, 1);
        s += __shfl_xor(s, 2);
        s += __shfl_xor(s, 4);
        s += __shfl_xor(s, 8);
        if (lr == 0)
            chanpart[(size_t)(b * 512 + mt * 64 + m) * 8 + nq * 2 + wn] = s + 32.f * bv;
    }
}

// Per (bg, p-chunk of 32): fc1+fc2 (redundant per chunk, cheap), sa dot over
// 256 channels, deterministic gsum partial.  512 blocks x 256 threads.
__global__ __launch_bounds__(256) void sa_kernel(
    const float* __restrict__ y4, const float* __restrict__ chanpart,
    const float* __restrict__ fc1w, const float* __restrict__ fc1b,
    const float* __restrict__ fc2w, const float* __restrict__ fc2b,
    const float* __restrict__ saw, const float* __restrict__ sab,
    float* __restrict__ ca, float* __restrict__ sa, float* __restrict__ gsums)
{
    const int blk = blockIdx.x;
    const int bg = blk >> 3, pc = blk & 7;
    const int b = bg >> 3, g = bg & 7;
    const int tid = threadIdx.x;
    const float* xg = y4 + ((size_t)b * 512 + (g & 1) * 256) * 256 + pc * 32;

    __shared__ float xl[256][32];
    __shared__ float avgs[256], red[256], hs[64], cas[256], caws[256], sas[32];

    // stage y4 slice [256c][32p]
#pragma unroll
    for (int i = 0; i < 8; ++i) {
        int f = i * 256 + tid;            // float4 id, 2048 total
        int c = f >> 3, p4 = f & 7;
        float4 v = *(const float4*)(xg + c * 256 + p4 * 4);
        *(float4*)(&xl[c][p4 * 4]) = v;
    }
    {
        const float* cpp = chanpart + (size_t)(b * 512 + (g & 1) * 256 + tid) * 8;
        float cp = 0.f;
#pragma unroll
        for (int i = 0; i < 8; ++i) cp += cpp[i];
        avgs[tid] = cp * (1.f / 256.f);
    }
    __syncthreads();
    // fc1: 256 -> 64, relu
    {
        int o = tid & 63, seg = tid >> 6;
        const float* wr = fc1w + (g * 64 + o) * 256 + seg * 64;
        const float* av = avgs + seg * 64;
        float s = 0.f;
#pragma unroll
        for (int i = 0; i < 64; ++i) s = fmaf(av[i], wr[i], s);
        red[tid] = s;
    }
    __syncthreads();
    if (tid < 64) {
        float s = fc1b[g * 64 + tid] + red[tid] + red[64 + tid] + red[128 + tid] + red[192 + tid];
        hs[tid] = fmaxf(s, 0.f);
    }
    __syncthreads();
    // fc2: 64 -> 256, sigmoid
    {
        const float* wr = fc2w + (g * 256 + tid) * 64;
        float s = fc2b[g * 256 + tid];
#pragma unroll
        for (int i = 0; i < 64; ++i) s = fmaf(hs[i], wr[i], s);
        float v = sigmoidf_(s);
        cas[tid] = v;
        caws[tid] = v * saw[g * 256 + tid];
        if (pc == 0) ca[bg * 256 + tid] = v;
    }
    __syncthreads();
    // sa dot over channels for 32 positions (from LDS)
    const int p_l = tid & 31, seg8 = tid >> 5;
    {
        float s = 0.f;
#pragma unroll
        for (int i = 0; i < 32; ++i) {
            int c = seg8 * 32 + i;
            s = fmaf(xl[c][p_l], caws[c], s);
        }
        red[tid] = s;
    }
    __syncthreads();
    if (tid < 32) {
        float s = sab[g];
#pragma unroll
        for (int k = 0; k < 8; ++k) s += red[k * 32 + tid];
        float v = sigmoidf_(s);
        sas[tid] = v;
        sa[bg * 256 + pc * 32 + tid] = v;
    }
    __syncthreads();
    // gsum partial: sum sigmoid(x*ca*sa) over this chunk's 32p x 256c
    {
        float sv = sas[p_l];
        float s = 0.f;
#pragma unroll
        for (int i = 0; i < 32; ++i) {
            int c = seg8 * 32 + i;
            s += sigmoidf_(xl[c][p_l] * cas[c] * sv);
        }
        red[tid] = s;
    }
    __syncthreads();
    for (int off = 128; off > 0; off >>= 1) {
        if (tid < off) red[tid] += red[tid + off];
        __syncthreads();
    }
    if (tid == 0) gsums[blk] = red[0];
}

// out = x*(1+mask); mask = (y>mean)?1:y, y = sigmoid(x*ca*sa).
// Dedup: each y4 float4 is read ONCE and expanded to its 4 output channels
// (g = parity, parity+2, parity+4, parity+6).  262144 threads total.
__global__ __launch_bounds__(256) void final_kernel(
    const float* __restrict__ y4, const float* __restrict__ ca,
    const float* __restrict__ sa, const float* __restrict__ gsums,
    float* __restrict__ out)
{
    int f = blockIdx.x * 256 + threadIdx.x;   // 0..262143: (b, c', p4)
    int p4 = f & 63;                          // float4 index within row
    int cp = (f >> 6) & 511;                  // unique y4 channel 0..511
    int b  = f >> 15;                         // batch 0..7
    int par = cp >> 8, c = cp & 255;
    const float4 x = *(const float4*)(y4 + ((size_t)b * 512 + cp) * 256 + p4 * 4);
#pragma unroll
    for (int gg = 0; gg < 4; ++gg) {
        const int g = par + gg * 2;
        const int bg = b * 8 + g;
        const float cav = ca[bg * 256 + c];
        const float4 sv = *(const float4*)(sa + bg * 256 + p4 * 4);
        float msum = 0.f;
#pragma unroll
        for (int i = 0; i < 8; ++i) msum += gsums[bg * 8 + i];
        const float mean = msum * (1.f / 65536.f);
        float4 o;
#define DOLANE(X) { float yv = sigmoidf_(x.X * cav * sv.X); float mk = (yv > mean) ? 1.f : yv; o.X = x.X * (1.f + mk); }
        DOLANE(x) DOLANE(y) DOLANE(z) DOLANE(w)
#undef DOLANE
        *(float4*)(out + ((size_t)b * 2048 + g * 256 + c) * 256 + p4 * 4) = o;
    }
}

extern "C" void kernel_launch(void* const* d_in, const int* in_sizes, int n_in,
                              void* d_out, int out_size, void* d_ws, size_t ws_size,
                              hipStream_t stream) {
    const float* x4   = (const float*)d_in[3];
    const float* w4   = (const float*)d_in[10];
    const float* b4   = (const float*)d_in[11];
    const float* fc1w = (const float*)d_in[12];
    const float* fc1b = (const float*)d_in[13];
    const float* fc2w = (const float*)d_in[14];
    const float* fc2b = (const float*)d_in[15];
    const float* saw  = (const float*)d_in[16];
    const float* sab  = (const float*)d_in[17];
    float* out = (float*)d_out;

    float* ws = (float*)d_ws;
    float* y4       = ws;                    // 1048576
    float* ca       = ws + 1048576;          // 16384
    float* saBuf    = ws + 1064960;          // 16384
    float* gsums    = ws + 1081344;          // 512
    float* chanpart = ws + 1081856;          // 32768

    gemm_fused<<<dim3(256), dim3(512), 0, stream>>>(x4, w4, b4, y4, chanpart);
    sa_kernel<<<dim3(512), dim3(256), 0, stream>>>(y4, chanpart, fc1w, fc1b, fc2w, fc2b,
                                                   saw, sab, ca, saBuf, gsums);
    final_kernel<<<dim3(1024), dim3(256), 0, stream>>>(y4, ca, saBuf, gsums, out);
}

// Round 13
// 43.246 us; speedup vs baseline: 1.2485x; 1.0234x over previous
//
#include <hip/hip_runtime.h>
#include <hip/hip_bf16.h>
#include <math.h>

typedef __attribute__((ext_vector_type(8))) short bf16x8;
typedef __attribute__((ext_vector_type(8))) unsigned short u16x8;
typedef __attribute__((ext_vector_type(4))) float f32x4;

__device__ __forceinline__ unsigned short f2bf(float f) {
    return __builtin_bit_cast(unsigned short, __float2bfloat16(f));
}

__device__ __forceinline__ float bf2f(unsigned short u) {
    unsigned int x = (unsigned int)u << 16;
    return __builtin_bit_cast(float, x);
}

__device__ __forceinline__ float sigmoidf_(float v) {
    return 1.f / (1.f + __expf(-v));
}

struct StageRegs { float4 w0, w1, x0, x1; };

// Fused convert+GEMM (r10/r12-proven structure).  y4[b][m][p] (bf16) =
// bias[m] + sum_k w[m][k]*x4[b][k][p].  Tile 64m x 64p, full K=2048, BK=64.
// 512 threads = 8 waves, each a 16m x 32p sub-tile.  T14 distance-2 register
// pipeline, one barrier per K-tile.  XOR-swizzled LDS tiles: elem (r,k) at
// r*64 + ((k>>3)^(r&7))*8 + (k&7) shorts.  Grid 256; blockIdx&7 = XCD = b.
__global__ __launch_bounds__(512) void gemm_fused(
    const float* __restrict__ x4, const float* __restrict__ w,
    const float* __restrict__ bias, unsigned short* __restrict__ y4,
    float* __restrict__ chanpart)
{
    __shared__ short As[2][4096];   // [buf][64m x 64k] swizzled
    __shared__ short Bs[2][4096];   // [buf][64p x 64k] swizzled

    const int tid = threadIdx.x;
    const int wave = tid >> 6, lane = tid & 63;
    const int wm = wave >> 1, wn = wave & 1;     // wm 0..3 (16m), wn 0..1 (32p)
    const int lr = lane & 15, lh = lane >> 4;

    const int flat = blockIdx.x;
    const int b = flat & 7;              // XCD-aligned batch
    const int j = flat >> 3;
    const int mt = j & 7;                // 0..7  (64-row chunk of M=512)
    const int nq = j >> 3;               // 0..3  (64-col chunk of one batch)

    // staging roles (512 threads)
    const int ar = tid >> 3, ac = tid & 7;    // A: row 0..63, k-chunk(8) 0..7
    const int ku = tid >> 4, xp4 = tid & 15;  // B: k-pair 0..31, p-quad 0..15

    const float* wbase = w + (size_t)(mt * 64 + ar) * 2048 + ac * 8;
    const float* xbase = x4 + ((size_t)b * 2048 + 2 * ku) * 256 + nq * 64 + xp4 * 4;

#define LOADT(R, t) {                                                         \
        (R).w0 = *(const float4*)(wbase + (t) * 64);                          \
        (R).w1 = *(const float4*)(wbase + (t) * 64 + 4);                      \
        (R).x0 = *(const float4*)(xbase + (size_t)(t) * 64 * 256);            \
        (R).x1 = *(const float4*)(xbase + (size_t)(t) * 64 * 256 + 256); }
#define WRITET(buf, R) {                                                      \
        u16x8 o;                                                              \
        o[0] = f2bf((R).w0.x); o[1] = f2bf((R).w0.y);                         \
        o[2] = f2bf((R).w0.z); o[3] = f2bf((R).w0.w);                         \
        o[4] = f2bf((R).w1.x); o[5] = f2bf((R).w1.y);                         \
        o[6] = f2bf((R).w1.z); o[7] = f2bf((R).w1.w);                         \
        *(u16x8*)(&As[buf][ar * 64 + ((ac ^ (ar & 7)) * 8)]) = o;             \
        unsigned int pk0 = f2bf((R).x0.x) | ((unsigned int)f2bf((R).x1.x) << 16); \
        unsigned int pk1 = f2bf((R).x0.y) | ((unsigned int)f2bf((R).x1.y) << 16); \
        unsigned int pk2 = f2bf((R).x0.z) | ((unsigned int)f2bf((R).x1.z) << 16); \
        unsigned int pk3 = f2bf((R).x0.w) | ((unsigned int)f2bf((R).x1.w) << 16); \
        unsigned int* bs32 = (unsigned int*)&Bs[buf][0];                      \
        { int p = xp4 * 4 + 0;                                                \
          bs32[p * 32 + ((ku >> 2) ^ (p & 7)) * 4 + (ku & 3)] = pk0; }        \
        { int p = xp4 * 4 + 1;                                                \
          bs32[p * 32 + ((ku >> 2) ^ (p & 7)) * 4 + (ku & 3)] = pk1; }        \
        { int p = xp4 * 4 + 2;                                                \
          bs32[p * 32 + ((ku >> 2) ^ (p & 7)) * 4 + (ku & 3)] = pk2; }        \
        { int p = xp4 * 4 + 3;                                                \
          bs32[p * 32 + ((ku >> 2) ^ (p & 7)) * 4 + (ku & 3)] = pk3; } }
#define MFMA_TILE(cur) {                                                      \
        _Pragma("unroll")                                                     \
        for (int kc = 0; kc < 2; ++kc) {                                      \
            const int ch = kc * 4 + lh;                                       \
            int rA  = wm * 16 + lr;                                           \
            int rB0 = wn * 32 + lr, rB1 = rB0 + 16;                           \
            bf16x8 a0 = *(const bf16x8*)(&As[cur][rA  * 64 + ((ch ^ (rA  & 7)) * 8)]); \
            bf16x8 b0 = *(const bf16x8*)(&Bs[cur][rB0 * 64 + ((ch ^ (rB0 & 7)) * 8)]); \
            bf16x8 b1 = *(const bf16x8*)(&Bs[cur][rB1 * 64 + ((ch ^ (rB1 & 7)) * 8)]); \
            acc0 = __builtin_amdgcn_mfma_f32_16x16x32_bf16(a0, b0, acc0, 0, 0, 0); \
            acc1 = __builtin_amdgcn_mfma_f32_16x16x32_bf16(a0, b1, acc1, 0, 0, 0); \
        } }

    StageRegs Ra, Rb;
    // Prologue: tile0 -> buf0 (via Ra), tile1 -> Rb, tile2 -> Ra (in flight)
    LOADT(Ra, 0);
    WRITET(0, Ra);
    LOADT(Rb, 1);
    LOADT(Ra, 2);
    __syncthreads();

    f32x4 acc0 = {}, acc1 = {};
    for (int t = 0; t < 32; t += 2) {
        // even: consume buf0 (tile t); write buf1 <- tile t+1 (Rb, loaded 2
        // iters ago, vmcnt satisfied); issue load tile t+3 -> Rb
        WRITET(1, Rb);
        if (t < 29) LOADT(Rb, t + 3);
        MFMA_TILE(0);
        __syncthreads();
        // odd: consume buf1 (tile t+1); write buf0 <- tile t+2 (Ra); load t+4
        if (t < 30) {
            WRITET(0, Ra);
            if (t < 28) LOADT(Ra, t + 4);
        }
        MFMA_TILE(1);
        __syncthreads();
    }
#undef LOADT
#undef WRITET
#undef MFMA_TILE

    unsigned short* yb = y4 + ((size_t)b * 512 + mt * 64) * 256 + nq * 64;
#pragma unroll
    for (int rr = 0; rr < 4; ++rr) {
        const int m = wm * 16 + lh * 4 + rr;      // within 64-row tile
        const float bv = bias[mt * 64 + m];
        yb[m * 256 + wn * 32 + lr]      = f2bf(acc0[rr] + bv);
        yb[m * 256 + wn * 32 + 16 + lr] = f2bf(acc1[rr] + bv);
        // wave-local sum over its 32 n positions (fp32, unchanged)
        float s = acc0[rr] + acc1[rr];
        s += __shfl_xor(s, 1);
        s += __shfl_xor(s, 2);
        s += __shfl_xor(s, 4);
        s += __shfl_xor(s, 8);
        if (lr == 0)
            chanpart[(size_t)(b * 512 + mt * 64 + m) * 8 + nq * 2 + wn] = s + 32.f * bv;
    }
}

// Per (bg, p-chunk of 32): fc1+fc2 (redundant per chunk, cheap), sa dot over
// 256 channels, deterministic gsum partial.  512 blocks x 256 threads.
// y4 is bf16; slice staged into LDS as fp32.
__global__ __launch_bounds__(256) void sa_kernel(
    const unsigned short* __restrict__ y4, const float* __restrict__ chanpart,
    const float* __restrict__ fc1w, const float* __restrict__ fc1b,
    const float* __restrict__ fc2w, const float* __restrict__ fc2b,
    const float* __restrict__ saw, const float* __restrict__ sab,
    float* __restrict__ ca, float* __restrict__ sa, float* __restrict__ gsums)
{
    const int blk = blockIdx.x;
    const int bg = blk >> 3, pc = blk & 7;
    const int b = bg >> 3, g = bg & 7;
    const int tid = threadIdx.x;
    const unsigned short* xg = y4 + ((size_t)b * 512 + (g & 1) * 256) * 256 + pc * 32;

    __shared__ float xl[256][32];
    __shared__ float avgs[256], red[256], hs[64], cas[256], caws[256], sas[32];

    // stage y4 slice [256c][32p] (bf16 -> fp32)
#pragma unroll
    for (int i = 0; i < 4; ++i) {
        int f = i * 256 + tid;            // ushort8 chunk id, 1024 total
        int c = f >> 2, jj = f & 3;
        u16x8 v = *(const u16x8*)(xg + c * 256 + jj * 8);
#pragma unroll
        for (int e = 0; e < 8; ++e) xl[c][jj * 8 + e] = bf2f(v[e]);
    }
    {
        const float* cpp = chanpart + (size_t)(b * 512 + (g & 1) * 256 + tid) * 8;
        float cp = 0.f;
#pragma unroll
        for (int i = 0; i < 8; ++i) cp += cpp[i];
        avgs[tid] = cp * (1.f / 256.f);
    }
    __syncthreads();
    // fc1: 256 -> 64, relu
    {
        int o = tid & 63, seg = tid >> 6;
        const float* wr = fc1w + (g * 64 + o) * 256 + seg * 64;
        const float* av = avgs + seg * 64;
        float s = 0.f;
#pragma unroll
        for (int i = 0; i < 64; ++i) s = fmaf(av[i], wr[i], s);
        red[tid] = s;
    }
    __syncthreads();
    if (tid < 64) {
        float s = fc1b[g * 64 + tid] + red[tid] + red[64 + tid] + red[128 + tid] + red[192 + tid];
        hs[tid] = fmaxf(s, 0.f);
    }
    __syncthreads();
    // fc2: 64 -> 256, sigmoid
    {
        const float* wr = fc2w + (g * 256 + tid) * 64;
        float s = fc2b[g * 256 + tid];
#pragma unroll
        for (int i = 0; i < 64; ++i) s = fmaf(hs[i], wr[i], s);
        float v = sigmoidf_(s);
        cas[tid] = v;
        caws[tid] = v * saw[g * 256 + tid];
        if (pc == 0) ca[bg * 256 + tid] = v;
    }
    __syncthreads();
    // sa dot over channels for 32 positions (from LDS)
    const int p_l = tid & 31, seg8 = tid >> 5;
    {
        float s = 0.f;
#pragma unroll
        for (int i = 0; i < 32; ++i) {
            int c = seg8 * 32 + i;
            s = fmaf(xl[c][p_l], caws[c], s);
        }
        red[tid] = s;
    }
    __syncthreads();
    if (tid < 32) {
        float s = sab[g];
#pragma unroll
        for (int k = 0; k < 8; ++k) s += red[k * 32 + tid];
        float v = sigmoidf_(s);
        sas[tid] = v;
        sa[bg * 256 + pc * 32 + tid] = v;
    }
    __syncthreads();
    // gsum partial: sum sigmoid(x*ca*sa) over this chunk's 32p x 256c
    {
        float sv = sas[p_l];
        float s = 0.f;
#pragma unroll
        for (int i = 0; i < 32; ++i) {
            int c = seg8 * 32 + i;
            s += sigmoidf_(xl[c][p_l] * cas[c] * sv);
        }
        red[tid] = s;
    }
    __syncthreads();
    for (int off = 128; off > 0; off >>= 1) {
        if (tid < off) red[tid] += red[tid + off];
        __syncthreads();
    }
    if (tid == 0) gsums[blk] = red[0];
}

// out = x*(1+mask); mask = (y>mean)?1:y, y = sigmoid(x*ca*sa).
// Dedup: each y4 element (bf16) read ONCE, expanded to its 4 output channels
// (g = parity, parity+2, parity+4, parity+6).  262144 threads total.
__global__ __launch_bounds__(256) void final_kernel(
    const unsigned short* __restrict__ y4, const float* __restrict__ ca,
    const float* __restrict__ sa, const float* __restrict__ gsums,
    float* __restrict__ out)
{
    int f = blockIdx.x * 256 + threadIdx.x;   // 0..262143: (b, c', p4)
    int p4 = f & 63;                          // quad index within row
    int cp = (f >> 6) & 511;                  // unique y4 channel 0..511
    int b  = f >> 15;                         // batch 0..7
    int par = cp >> 8, c = cp & 255;
    const ushort4 xu = *(const ushort4*)(y4 + ((size_t)b * 512 + cp) * 256 + p4 * 4);
    const float x0 = bf2f(xu.x), x1 = bf2f(xu.y), x2 = bf2f(xu.z), x3 = bf2f(xu.w);
#pragma unroll
    for (int gg = 0; gg < 4; ++gg) {
        const int g = par + gg * 2;
        const int bg = b * 8 + g;
        const float cav = ca[bg * 256 + c];
        const float4 sv = *(const float4*)(sa + bg * 256 + p4 * 4);
        float msum = 0.f;
#pragma unroll
        for (int i = 0; i < 8; ++i) msum += gsums[bg * 8 + i];
        const float mean = msum * (1.f / 65536.f);
        float4 o;
#define DOLANE(OX, XV, SX) { float yv = sigmoidf_((XV) * cav * sv.SX); \
        float mk = (yv > mean) ? 1.f : yv; o.OX = (XV) * (1.f + mk); }
        DOLANE(x, x0, x) DOLANE(y, x1, y) DOLANE(z, x2, z) DOLANE(w, x3, w)
#undef DOLANE
        *(float4*)(out + ((size_t)b * 2048 + g * 256 + c) * 256 + p4 * 4) = o;
    }
}

extern "C" void kernel_launch(void* const* d_in, const int* in_sizes, int n_in,
                              void* d_out, int out_size, void* d_ws, size_t ws_size,
                              hipStream_t stream) {
    const float* x4   = (const float*)d_in[3];
    const float* w4   = (const float*)d_in[10];
    const float* b4   = (const float*)d_in[11];
    const float* fc1w = (const float*)d_in[12];
    const float* fc1b = (const float*)d_in[13];
    const float* fc2w = (const float*)d_in[14];
    const float* fc2b = (const float*)d_in[15];
    const float* saw  = (const float*)d_in[16];
    const float* sab  = (const float*)d_in[17];
    float* out = (float*)d_out;

    float* ws = (float*)d_ws;
    unsigned short* y4 = (unsigned short*)ws;  // 1048576 bf16 (= 524288 floats)
    float* ca       = ws + 524288;           // 16384
    float* saBuf    = ws + 540672;           // 16384
    float* gsums    = ws + 557056;           // 512
    float* chanpart = ws + 557568;           // 32768

    gemm_fused<<<dim3(256), dim3(512), 0, stream>>>(x4, w4, b4, y4, chanpart);
    sa_kernel<<<dim3(512), dim3(256), 0, stream>>>(y4, chanpart, fc1w, fc1b, fc2w, fc2b,
                                                   saw, sab, ca, saBuf, gsums);
    final_kernel<<<dim3(1024), dim3(256), 0, stream>>>(y4, ca, saBuf, gsums, out);
}